// Round 3
// baseline (116.934 us; speedup 1.0000x reference)
//
#include <hip/hip_runtime.h>
#include <hip/hip_fp16.h>
#include <math.h>

#define D_FEAT 128

typedef _Float16 half2_t __attribute__((ext_vector_type(2)));

// |a-b| for a packed pair of fp16, accumulated into fp32 via v_dot2_f32_f16
__device__ __forceinline__ float l1_u(unsigned int ua, unsigned int ub, float acc) {
    half2_t a = __builtin_bit_cast(half2_t, ua);
    half2_t b = __builtin_bit_cast(half2_t, ub);
    half2_t d = a - b;                                   // v_pk_add_f16 (neg)
    unsigned int du = __builtin_bit_cast(unsigned int, d) & 0x7fff7fffu;  // |.| packed
    half2_t ad = __builtin_bit_cast(half2_t, du);
    const half2_t one = {(_Float16)1.0f, (_Float16)1.0f};
    return __builtin_amdgcn_fdot2(ad, one, acc, false);  // acc += ad.x + ad.y
}

__device__ __forceinline__ float l1_u4(uint4 a, uint4 b, float acc) {
    acc = l1_u(a.x, b.x, acc);
    acc = l1_u(a.y, b.y, acc);
    acc = l1_u(a.z, b.z, acc);
    acc = l1_u(a.w, b.w, acc);
    return acc;
}

__device__ __forceinline__ unsigned int pkh(float x, float y) {
    __half2 h = __halves2half2(__float2half_rn(x), __float2half_rn(y));
    return __builtin_bit_cast(unsigned int, h);
}

// ---------------------------------------------------------------------------
// Phase 0: init s = 0; convert feats fp32 -> fp16 shadow (RNE). fp16 has 8x
// finer mantissa than bf16 at identical gather traffic; data is N(0,1) so no
// range issues. One thread per 8 floats.
// ---------------------------------------------------------------------------
__global__ __launch_bounds__(256) void prep_kernel(
    const float* __restrict__ feats, unsigned int* __restrict__ fh,
    float* __restrict__ s, int n_nodes, int n_vec)
{
    int i = blockIdx.x * blockDim.x + threadIdx.x;
    if (i < n_nodes) s[i] = 0.0f;
    if (i < n_vec) {
        const float4* fp = (const float4*)feats;
        float4 a = fp[2 * i];
        float4 b = fp[2 * i + 1];
        uint4 o;
        o.x = pkh(a.x, a.y);
        o.y = pkh(a.z, a.w);
        o.z = pkh(b.x, b.y);
        o.w = pkh(b.z, b.w);
        ((uint4*)fh)[i] = o;
    }
}

// ---------------------------------------------------------------------------
// Phase 1: w = exp(exp(-0.01 * L1(feats[src]-feats[dst]))) per edge; atomic
// segment-sum into s[dst]. No segment-max needed (e in (0,1] => overflow-free
// and mathematically identical to the max-subtracted softmax).
//
// 8 lanes per edge, 2 edges per thread: each thread issues 8 independent
// 16B loads (4 per edge: src row halves l and l+8, dst row same) before any
// reduction -> 4x the memory-level parallelism of the R2 kernel, probing
// whether the ~3.5 TB/s L2-miss-path rate was concurrency-limited.
// fp16 row = 256B = 16 uint4; lane l takes uint4 l and l+8.
// Butterfly reduce with xor masks 4,2,1 (stays within the 8-lane group).
// ---------------------------------------------------------------------------
__global__ __launch_bounds__(256) void edge_kernel(
    const unsigned int* __restrict__ fh, const int* __restrict__ src,
    const int* __restrict__ dst, float* __restrict__ out,
    float* __restrict__ s, int n_edges)
{
    int tid = blockIdx.x * blockDim.x + threadIdx.x;
    int l   = tid & 7;          // lane within 8-lane group
    int g   = tid >> 3;         // group id
    int e0  = g * 2;
    int e1  = e0 + 1;
    if (e0 >= n_edges) return;
    bool have1 = (e1 < n_edges);

    int s0 = src[e0], d0 = dst[e0];
    int s1 = have1 ? src[e1] : s0;
    int d1 = have1 ? dst[e1] : d0;

    const uint4* t = (const uint4*)fh;   // table as 16B chunks; row = 16 chunks
    // issue all 8 loads up front (independent -> deep MLP)
    uint4 sa0 = t[(size_t)s0 * 16 + l];
    uint4 sb0 = t[(size_t)s0 * 16 + l + 8];
    uint4 da0 = t[(size_t)d0 * 16 + l];
    uint4 db0 = t[(size_t)d0 * 16 + l + 8];
    uint4 sa1 = t[(size_t)s1 * 16 + l];
    uint4 sb1 = t[(size_t)s1 * 16 + l + 8];
    uint4 da1 = t[(size_t)d1 * 16 + l];
    uint4 db1 = t[(size_t)d1 * 16 + l + 8];

    float p0 = 0.0f, p1 = 0.0f;
    p0 = l1_u4(sa0, da0, p0);
    p0 = l1_u4(sb0, db0, p0);
    p1 = l1_u4(sa1, da1, p1);
    p1 = l1_u4(sb1, db1, p1);

    #pragma unroll
    for (int mask = 4; mask >= 1; mask >>= 1) {
        p0 += __shfl_xor(p0, mask);
        p1 += __shfl_xor(p1, mask);
    }

    if (l == 0) {
        float w0 = expf(expf(-0.01f * p0));
        out[e0] = w0;
        atomicAdd(s + d0, w0);
        if (have1) {
            float w1 = expf(expf(-0.01f * p1));
            out[e1] = w1;
            atomicAdd(s + d1, w1);
        }
    }
}

// ---------------------------------------------------------------------------
// Phase 2: out = w / s[dst]
// ---------------------------------------------------------------------------
__global__ void norm_kernel(const int* __restrict__ dst, const float* __restrict__ s,
                            float* __restrict__ out, int n_edges)
{
    int i = blockIdx.x * blockDim.x + threadIdx.x;
    if (i >= n_edges) return;
    out[i] = out[i] / s[dst[i]];
}

extern "C" void kernel_launch(void* const* d_in, const int* in_sizes, int n_in,
                              void* d_out, int out_size, void* d_ws, size_t ws_size,
                              hipStream_t stream) {
    const float* feats = (const float*)d_in[0];
    const int*   src   = (const int*)d_in[1];
    const int*   dst   = (const int*)d_in[2];
    float* out = (float*)d_out;

    int n_edges = in_sizes[1];
    int n_nodes = in_sizes[0] / D_FEAT;
    int n_vec   = n_nodes * (D_FEAT / 8);   // 8 floats per prep thread

    // ws layout: s [n_nodes floats] | fh [n_nodes * 64 uints] (fp16-packed)
    float* sseg = (float*)d_ws;
    unsigned int* fh = (unsigned int*)((char*)d_ws + (size_t)n_nodes * sizeof(float));

    prep_kernel<<<(n_vec + 255) / 256, 256, 0, stream>>>(feats, fh, sseg, n_nodes, n_vec);

    // 8 lanes/edge, 2 edges/thread -> 4 threads per edge
    long long threads = ((long long)n_edges + 1) / 2 * 8;
    int n_blocks_edge = (int)((threads + 255) / 256);
    edge_kernel<<<n_blocks_edge, 256, 0, stream>>>(fh, src, dst, out, sseg, n_edges);

    norm_kernel<<<(n_edges + 255) / 256, 256, 0, stream>>>(dst, sseg, out, n_edges);
}